// Round 8
// baseline (456.045 us; speedup 1.0000x reference)
//
#include <hip/hip_runtime.h>
#include <math.h>

#define N_NODES 50000
#define N_EDGES 1000000
#define HID 64
#define SCAN_NB ((N_NODES + 1 + 255) / 256)
#define NBP 128   // pool blocks
static_assert(N_NODES <= 65536, "src must fit in 16 bits");

typedef __attribute__((ext_vector_type(8))) short short8;   // 8 bf16 = 4 VGPRs
typedef __attribute__((ext_vector_type(4))) float f32x4;

__device__ __forceinline__ unsigned short f2bf(float x) {   // RNE float->bf16
    unsigned u = __float_as_uint(x);
    u += 0x7FFFu + ((u >> 16) & 1u);
    return (unsigned short)(u >> 16);
}
__device__ __forceinline__ float bfbits_hi(unsigned pk) {   // high-16 bf16 -> f32
    return __uint_as_float(pk & 0xFFFF0000u);
}
__device__ __forceinline__ float bf2f(unsigned short v) {
    return __uint_as_float(((unsigned)v) << 16);
}

__device__ __forceinline__ float waveReduceSum64(float v) {
    #pragma unroll
    for (int o = 32; o > 0; o >>= 1) v += __shfl_xor(v, o, 64);
    return v;
}

// ---------------- node encoder: h = x @ W_node + b_node (f32 + bf16 copies) ----------------
__global__ __launch_bounds__(256) void k_node_encode(
    const float* __restrict__ x, const float* __restrict__ Wn,
    const float* __restrict__ bn, float* __restrict__ h, unsigned short* __restrict__ hb) {
    int n = blockIdx.x * 4 + (threadIdx.x >> 6);
    int c = threadIdx.x & 63;
    if (n >= N_NODES) return;
    float acc = bn[c];
    const float* xr = x + n * 16;
    #pragma unroll
    for (int k = 0; k < 16; ++k) acc = fmaf(xr[k], Wn[k * 64 + c], acc);
    h[n * 64 + c] = acc;
    hb[n * 64 + c] = f2bf(acc);
}

// ---------------- edge CSR build: histogram + per-edge rank ----------------
__global__ __launch_bounds__(256) void k_hist_rank(const int* __restrict__ ei,
                                                   int* __restrict__ cnt, int* __restrict__ rank) {
    int i = blockIdx.x * blockDim.x + threadIdx.x;
    if (i >= N_EDGES) return;
    rank[i] = atomicAdd(&cnt[ei[N_EDGES + i]], 1);
}

__global__ __launch_bounds__(256) void k_scan1(const int* __restrict__ cnt,
                                               int* __restrict__ inc, int* __restrict__ bsum) {
    __shared__ int sh[256];
    int gi = blockIdx.x * 256 + threadIdx.x;
    int v = (gi < N_NODES + 1) ? cnt[gi] : 0;
    sh[threadIdx.x] = v;
    __syncthreads();
    #pragma unroll
    for (int d = 1; d < 256; d <<= 1) {
        int t = (threadIdx.x >= d) ? sh[threadIdx.x - d] : 0;
        __syncthreads();
        sh[threadIdx.x] += t;
        __syncthreads();
    }
    if (gi < N_NODES + 1) inc[gi] = sh[threadIdx.x];
    if (threadIdx.x == 255) bsum[blockIdx.x] = sh[255];
}

__global__ __launch_bounds__(256) void k_scan2(int* __restrict__ bsum) {
    __shared__ int sh[256];
    int t = threadIdx.x;
    sh[t] = (t < SCAN_NB) ? bsum[t] : 0;
    __syncthreads();
    #pragma unroll
    for (int d = 1; d < 256; d <<= 1) {
        int v = (t >= d) ? sh[t - d] : 0;
        __syncthreads();
        sh[t] += v;
        __syncthreads();
    }
    if (t < SCAN_NB) bsum[t] = (t == 0) ? 0 : sh[t - 1];
}

__global__ __launch_bounds__(256) void k_scan3(const int* __restrict__ inc,
                                               const int* __restrict__ cnt,
                                               const int* __restrict__ bsum,
                                               int* __restrict__ offs) {
    int gi = blockIdx.x * 256 + threadIdx.x;
    if (gi < N_NODES + 1) offs[gi] = bsum[blockIdx.x] + inc[gi] - cnt[gi];
}

// pure random 4B store, no atomics: p = offs[d] + rank[i]
__global__ __launch_bounds__(256) void k_scatter(
    const int* __restrict__ ei, const float* __restrict__ eattr,
    const int* __restrict__ offs, const int* __restrict__ rank,
    unsigned int* __restrict__ s_pack) {
    int i = blockIdx.x * blockDim.x + threadIdx.x;
    if (i >= N_EDGES) return;
    int d = ei[N_EDGES + i];
    int p = offs[d] + rank[i];
    unsigned pk = ((unsigned)f2bf(eattr[i]) << 16) | (unsigned)(ei[i] & 0xFFFF);
    s_pack[p] = pk;
}

// ---------------- z = relu(LN(h, g, b)) (f32 + bf16 copies) ----------------
__global__ __launch_bounds__(256) void k_ln_relu(
    const float* __restrict__ h, const float* __restrict__ g,
    const float* __restrict__ b, float* __restrict__ z, unsigned short* __restrict__ zb) {
    int wid = (blockIdx.x * blockDim.x + threadIdx.x) >> 6;
    int lane = threadIdx.x & 63;
    if (wid >= N_NODES) return;
    float v = h[wid * 64 + lane];
    float mu = waveReduceSum64(v) * (1.f / 64.f);
    float d = v - mu;
    float var = waveReduceSum64(d * d) * (1.f / 64.f);
    float zz = fmaxf(d * rsqrtf(var + 1e-5f) * g[lane] + b[lane], 0.f);
    z[wid * 64 + lane] = zz;
    zb[wid * 64 + lane] = f2bf(zz);
}

// ---------------- softmax aggregation, online, one wave per dst node ----------------
__global__ __launch_bounds__(256) void k_agg(
    const unsigned short* __restrict__ zb, const int* __restrict__ offs,
    const unsigned int* __restrict__ s_pack,
    const float* __restrict__ We, const float* __restrict__ be,
    const float* __restrict__ t, int layer, float* __restrict__ agg) {
    int wid = (blockIdx.x * blockDim.x + threadIdx.x) >> 6;
    int lane = threadIdx.x & 63;
    if (wid >= N_NODES) return;
    int beg = offs[wid], end = offs[wid + 1];
    float we = We[lane], bev = be[lane];
    float tl = t[layer];
    float m = -INFINITY, s = 0.f, num = 0.f;
    int i = beg;
    for (; i + 3 < end; i += 4) {
        unsigned pk0 = s_pack[i], pk1 = s_pack[i + 1], pk2 = s_pack[i + 2], pk3 = s_pack[i + 3];
        float z0 = bf2f(zb[(pk0 & 0xFFFFu) * 64 + lane]);
        float z1 = bf2f(zb[(pk1 & 0xFFFFu) * 64 + lane]);
        float z2 = bf2f(zb[(pk2 & 0xFFFFu) * 64 + lane]);
        float z3 = bf2f(zb[(pk3 & 0xFFFFu) * 64 + lane]);
        float msg0 = fmaxf(z0 + fmaf(bfbits_hi(pk0), we, bev), 0.f) + 1e-7f;
        float msg1 = fmaxf(z1 + fmaf(bfbits_hi(pk1), we, bev), 0.f) + 1e-7f;
        float msg2 = fmaxf(z2 + fmaf(bfbits_hi(pk2), we, bev), 0.f) + 1e-7f;
        float msg3 = fmaxf(z3 + fmaf(bfbits_hi(pk3), we, bev), 0.f) + 1e-7f;
        float lg0 = msg0 * tl, lg1 = msg1 * tl, lg2 = msg2 * tl, lg3 = msg3 * tl;
        float mn = fmaxf(m, fmaxf(fmaxf(lg0, lg1), fmaxf(lg2, lg3)));
        float corr = __expf(m - mn);
        float p0 = __expf(lg0 - mn), p1 = __expf(lg1 - mn);
        float p2 = __expf(lg2 - mn), p3 = __expf(lg3 - mn);
        s = fmaf(s, corr, (p0 + p1) + (p2 + p3));
        num = fmaf(num, corr, fmaf(p0, msg0, p1 * msg1) + fmaf(p2, msg2, p3 * msg3));
        m = mn;
    }
    for (; i < end; ++i) {
        unsigned pk = s_pack[i];
        float zz = bf2f(zb[(pk & 0xFFFFu) * 64 + lane]);
        float msg = fmaxf(zz + fmaf(bfbits_hi(pk), we, bev), 0.f) + 1e-7f;
        float lg = msg * tl;
        float mn = fmaxf(m, lg);
        float corr = __expf(m - mn);
        float p = __expf(lg - mn);
        s = fmaf(s, corr, p);
        num = fmaf(num, corr, p * msg);
        m = mn;
    }
    agg[wid * 64 + lane] = num / (s + 1e-16f);
}

// ---------------- fused MLP via MFMA bf16 (one wave per 16 nodes) ----------------
__global__ __launch_bounds__(256) void k_mlp(
    const float* __restrict__ agg, const float* __restrict__ z,
    float* __restrict__ h, const float* __restrict__ W1, const float* __restrict__ b1,
    const float* __restrict__ g1, const float* __restrict__ be1,
    const float* __restrict__ W2, const float* __restrict__ b2, int addres) {
    __shared__ unsigned short vbuf[4][16 * 64];
    __shared__ unsigned short ubuf[4][16 * 128];
    int lane = threadIdx.x & 63;
    int wave = threadIdx.x >> 6;
    int col = lane & 15, quad = lane >> 4;
    unsigned short* vb = vbuf[wave];
    unsigned short* ub = ubuf[wave];

    short8 w1f[2][8];
    #pragma unroll
    for (int s = 0; s < 2; ++s)
        #pragma unroll
        for (int t = 0; t < 8; ++t)
            #pragma unroll
            for (int j = 0; j < 8; ++j)
                w1f[s][t][j] = (short)f2bf(W1[(s * 32 + quad * 8 + j) * 128 + t * 16 + col]);
    short8 w2f[4][4];
    #pragma unroll
    for (int s = 0; s < 4; ++s)
        #pragma unroll
        for (int t = 0; t < 4; ++t)
            #pragma unroll
            for (int j = 0; j < 8; ++j)
                w2f[s][t][j] = (short)f2bf(W2[(s * 32 + quad * 8 + j) * 64 + t * 16 + col]);

    float b1f[8], g1f[8], e1f[8];
    #pragma unroll
    for (int t = 0; t < 8; ++t) {
        int ch = t * 16 + col;
        b1f[t] = b1[ch]; g1f[t] = g1[ch]; e1f[t] = be1[ch];
    }
    float b2f_[4];
    #pragma unroll
    for (int t = 0; t < 4; ++t) b2f_[t] = b2[t * 16 + col];

    int nd = lane >> 2;
    int cg = (lane & 3) * 16;

    for (int g = blockIdx.x * 4 + wave; g < N_NODES / 16; g += gridDim.x * 4) {
        int n0 = g * 16;
        const float4* ap = (const float4*)(agg + (size_t)(n0 + nd) * 64 + cg);
        const float4* zp = (const float4*)(z + (size_t)(n0 + nd) * 64 + cg);
        float vv[16];
        #pragma unroll
        for (int q = 0; q < 4; ++q) {
            float4 a4 = ap[q], z4 = zp[q];
            vv[q * 4 + 0] = a4.x + z4.x; vv[q * 4 + 1] = a4.y + z4.y;
            vv[q * 4 + 2] = a4.z + z4.z; vv[q * 4 + 3] = a4.w + z4.w;
        }
        unsigned int pk[8];
        #pragma unroll
        for (int i = 0; i < 8; ++i)
            pk[i] = (unsigned)f2bf(vv[2 * i]) | ((unsigned)f2bf(vv[2 * i + 1]) << 16);
        uint4* vdst = (uint4*)&vb[nd * 64 + cg];
        vdst[0] = make_uint4(pk[0], pk[1], pk[2], pk[3]);
        vdst[1] = make_uint4(pk[4], pk[5], pk[6], pk[7]);

        short8 a0 = *(const short8*)&vb[col * 64 + quad * 8];
        short8 a1 = *(const short8*)&vb[col * 64 + 32 + quad * 8];
        f32x4 au[8];
        #pragma unroll
        for (int t = 0; t < 8; ++t) {
            f32x4 c = {0.f, 0.f, 0.f, 0.f};
            c = __builtin_amdgcn_mfma_f32_16x16x32_bf16(a0, w1f[0][t], c, 0, 0, 0);
            c = __builtin_amdgcn_mfma_f32_16x16x32_bf16(a1, w1f[1][t], c, 0, 0, 0);
            au[t] = c;
        }
        #pragma unroll
        for (int r = 0; r < 4; ++r) {
            float sx = 0.f, sq = 0.f;
            #pragma unroll
            for (int t = 0; t < 8; ++t) {
                float v = au[t][r] + b1f[t];
                sx += v; sq += v * v;
            }
            #pragma unroll
            for (int mask = 1; mask < 16; mask <<= 1) {
                sx += __shfl_xor(sx, mask, 64);
                sq += __shfl_xor(sq, mask, 64);
            }
            float mu = sx * (1.f / 128.f);
            float var = sq * (1.f / 128.f) - mu * mu;
            float rs = rsqrtf(var + 1e-5f);
            int row = quad * 4 + r;
            #pragma unroll
            for (int t = 0; t < 8; ++t) {
                float v = au[t][r] + b1f[t];
                float y = fmaxf(fmaf((v - mu) * rs, g1f[t], e1f[t]), 0.f);
                ub[row * 128 + t * 16 + col] = f2bf(y);
            }
        }
        f32x4 oc[4];
        #pragma unroll
        for (int t = 0; t < 4; ++t) oc[t] = (f32x4){0.f, 0.f, 0.f, 0.f};
        #pragma unroll
        for (int s = 0; s < 4; ++s) {
            short8 a = *(const short8*)&ub[col * 128 + s * 32 + quad * 8];
            #pragma unroll
            for (int t = 0; t < 4; ++t)
                oc[t] = __builtin_amdgcn_mfma_f32_16x16x32_bf16(a, w2f[s][t], oc[t], 0, 0, 0);
        }
        #pragma unroll
        for (int t = 0; t < 4; ++t) {
            #pragma unroll
            for (int r = 0; r < 4; ++r) {
                int n = n0 + quad * 4 + r;
                int ch = t * 16 + col;
                float val = oc[t][r] + b2f_[t];
                float* hp = &h[(size_t)n * 64 + ch];
                if (addres) val += *hp;
                *hp = val;
            }
        }
    }
}

// ---------------- final LN/relu + pool partials (block-reduced, no atomics) ----------------
__global__ __launch_bounds__(256) void k_pool(
    const float* __restrict__ h, const float* __restrict__ g, const float* __restrict__ b,
    float* __restrict__ pb_sum, float* __restrict__ pb_max) {
    __shared__ float ssum[4][64];
    __shared__ float smax[4][64];
    int lane = threadIdx.x & 63;
    int wave = threadIdx.x >> 6;
    int gw = blockIdx.x * 4 + wave;
    int nw = gridDim.x * 4;
    float ga = g[lane], ba = b[lane];
    float lsum = 0.f, lmax = 0.f;
    for (int n = gw; n < N_NODES; n += nw) {
        float v = h[n * 64 + lane];
        float mu = waveReduceSum64(v) * (1.f / 64.f);
        float d = v - mu;
        float var = waveReduceSum64(d * d) * (1.f / 64.f);
        float zz = fmaxf(d * rsqrtf(var + 1e-5f) * ga + ba, 0.f);
        lsum += zz;
        lmax = fmaxf(lmax, zz);
    }
    ssum[wave][lane] = lsum;
    smax[wave][lane] = lmax;
    __syncthreads();
    if (wave == 0) {
        float s = ssum[0][lane] + ssum[1][lane] + ssum[2][lane] + ssum[3][lane];
        float mx = fmaxf(fmaxf(smax[0][lane], smax[1][lane]),
                         fmaxf(smax[2][lane], smax[3][lane]));
        pb_sum[blockIdx.x * 64 + lane] = s;
        pb_max[blockIdx.x * 64 + lane] = mx;
    }
}

// ---------------- head: reduce block partials -> bins -> emb @ W_lin + b_lin ----------------
__global__ __launch_bounds__(64) void k_head(
    const float* __restrict__ pb_sum, const float* __restrict__ pb_max,
    const float* __restrict__ Wl, const float* __restrict__ bl, float* __restrict__ out) {
    __shared__ float sa[64], sm[64], emb[64];
    int t = threadIdx.x;
    float s = 0.f, mx = 0.f;
    for (int b = 0; b < NBP; ++b) {
        s += pb_sum[b * 64 + t];
        mx = fmaxf(mx, pb_max[b * 64 + t]);
    }
    sa[t] = s; sm[t] = mx;
    __syncthreads();
    if (t < 32) {
        emb[t] = (sa[2 * t] + sa[2 * t + 1]) * (0.5f / (float)N_NODES);
    } else {
        int i = t - 32;
        emb[t] = fmaxf(sm[2 * i], sm[2 * i + 1]);
    }
    __syncthreads();
    float acc = bl[t];
    for (int k = 0; k < 64; ++k) acc = fmaf(emb[k], Wl[k * 64 + t], acc);
    out[t] = acc;
}

extern "C" void kernel_launch(void* const* d_in, const int* in_sizes, int n_in,
                              void* d_out, int out_size, void* d_ws, size_t ws_size,
                              hipStream_t stream) {
    const float* x     = (const float*)d_in[0];
    const float* eattr = (const float*)d_in[1];
    const int*   ei    = (const int*)d_in[2];
    const float* Wn    = (const float*)d_in[3];
    const float* bn    = (const float*)d_in[4];
    const float* We    = (const float*)d_in[5];
    const float* be    = (const float*)d_in[6];
    const float* t     = (const float*)d_in[7];
    const float* W1    = (const float*)d_in[8];
    const float* b1    = (const float*)d_in[9];
    const float* lg    = (const float*)d_in[10];
    const float* lb    = (const float*)d_in[11];
    const float* W2    = (const float*)d_in[12];
    const float* b2    = (const float*)d_in[13];
    const float* ng    = (const float*)d_in[14];
    const float* nb    = (const float*)d_in[15];
    const float* Wl    = (const float*)d_in[16];
    const float* bl    = (const float*)d_in[17];
    float* out = (float*)d_out;

    char* p = (char*)d_ws;
    float* h   = (float*)p; p += (size_t)N_NODES * 64 * 4;
    float* z   = (float*)p; p += (size_t)N_NODES * 64 * 4;
    float* agg = (float*)p; p += (size_t)N_NODES * 64 * 4;
    unsigned short* zb = (unsigned short*)p; p += (size_t)N_NODES * 64 * 2;
    unsigned int* s_pack = (unsigned int*)p; p += (size_t)N_EDGES * 4;
    int* cnt    = (int*)p;  p += (size_t)(N_NODES + 4) * 4;
    int* offs   = (int*)p;  p += (size_t)(N_NODES + 4) * 4;
    int* inc    = (int*)p;  p += (size_t)(N_NODES + 4) * 4;
    int* bsum   = (int*)p;  p += (size_t)256 * 4;
    float* pb_sum = (float*)p; p += (size_t)NBP * 64 * 4;
    float* pb_max = (float*)p; p += (size_t)NBP * 64 * 4;
    int* rank = (int*)agg;   // aliases agg: rank dead before first k_agg write

    hipMemsetAsync(cnt, 0, (N_NODES + 1) * sizeof(int), stream);

    k_node_encode<<<(N_NODES + 3) / 4, 256, 0, stream>>>(x, Wn, bn, h, zb);
    k_hist_rank<<<(N_EDGES + 255) / 256, 256, 0, stream>>>(ei, cnt, rank);
    k_scan1<<<SCAN_NB, 256, 0, stream>>>(cnt, inc, bsum);
    k_scan2<<<1, 256, 0, stream>>>(bsum);
    k_scan3<<<SCAN_NB, 256, 0, stream>>>(inc, cnt, bsum, offs);
    k_scatter<<<(N_EDGES + 255) / 256, 256, 0, stream>>>(ei, eattr, offs, rank, s_pack);

    for (int i = 0; i < 3; ++i) {
        const float* zp;
        if (i > 0) {
            k_ln_relu<<<(N_NODES + 3) / 4, 256, 0, stream>>>(h, ng + i * 64, nb + i * 64, z, zb);
            zp = z;
        } else {
            zp = h;   // zb already holds bf16(h) from k_node_encode
        }
        k_agg<<<(N_NODES + 3) / 4, 256, 0, stream>>>(zb, offs, s_pack, We, be, t, i, agg);
        k_mlp<<<391, 256, 0, stream>>>(
            agg, zp, h, W1 + (size_t)i * 64 * 128, b1 + i * 128, lg + i * 128, lb + i * 128,
            W2 + (size_t)i * 128 * 64, b2 + i * 64, i > 0);
    }

    k_pool<<<NBP, 256, 0, stream>>>(h, ng, nb, pb_sum, pb_max);
    k_head<<<1, 64, 0, stream>>>(pb_sum, pb_max, Wl, bl, out);
}

// Round 9
// 430.070 us; speedup vs baseline: 1.0604x; 1.0604x over previous
//
#include <hip/hip_runtime.h>
#include <math.h>

#define N_NODES 50000
#define N_EDGES 1000000
#define HID 64
#define SCAN_NB ((N_NODES + 1 + 255) / 256)
#define NBP 512   // pool blocks (2 per CU)
static_assert(N_NODES <= 65536, "src must fit in 16 bits");

typedef __attribute__((ext_vector_type(8))) short short8;   // 8 bf16 = 4 VGPRs
typedef __attribute__((ext_vector_type(4))) float f32x4;

__device__ __forceinline__ unsigned short f2bf(float x) {   // RNE float->bf16
    unsigned u = __float_as_uint(x);
    u += 0x7FFFu + ((u >> 16) & 1u);
    return (unsigned short)(u >> 16);
}
__device__ __forceinline__ float bfbits_hi(unsigned pk) {   // high-16 bf16 -> f32
    return __uint_as_float(pk & 0xFFFF0000u);
}
__device__ __forceinline__ float bf2f(unsigned short v) {
    return __uint_as_float(((unsigned)v) << 16);
}

__device__ __forceinline__ float waveReduceSum64(float v) {
    #pragma unroll
    for (int o = 32; o > 0; o >>= 1) v += __shfl_xor(v, o, 64);
    return v;
}

// ---------------- node encoder: h = x @ W_node + b_node (f32 + bf16 copies) ----------------
__global__ __launch_bounds__(256) void k_node_encode(
    const float* __restrict__ x, const float* __restrict__ Wn,
    const float* __restrict__ bn, float* __restrict__ h, unsigned short* __restrict__ hb) {
    int n = blockIdx.x * 4 + (threadIdx.x >> 6);
    int c = threadIdx.x & 63;
    if (n >= N_NODES) return;
    float acc = bn[c];
    const float* xr = x + n * 16;
    #pragma unroll
    for (int k = 0; k < 16; ++k) acc = fmaf(xr[k], Wn[k * 64 + c], acc);
    h[n * 64 + c] = acc;
    hb[n * 64 + c] = f2bf(acc);
}

// ---------------- edge CSR build: histogram + per-edge rank ----------------
__global__ __launch_bounds__(256) void k_hist_rank(const int* __restrict__ ei,
                                                   int* __restrict__ cnt, int* __restrict__ rank) {
    int i = blockIdx.x * blockDim.x + threadIdx.x;
    if (i >= N_EDGES) return;
    rank[i] = atomicAdd(&cnt[ei[N_EDGES + i]], 1);
}

__global__ __launch_bounds__(256) void k_scan1(const int* __restrict__ cnt,
                                               int* __restrict__ inc, int* __restrict__ bsum) {
    __shared__ int sh[256];
    int gi = blockIdx.x * 256 + threadIdx.x;
    int v = (gi < N_NODES + 1) ? cnt[gi] : 0;
    sh[threadIdx.x] = v;
    __syncthreads();
    #pragma unroll
    for (int d = 1; d < 256; d <<= 1) {
        int t = (threadIdx.x >= d) ? sh[threadIdx.x - d] : 0;
        __syncthreads();
        sh[threadIdx.x] += t;
        __syncthreads();
    }
    if (gi < N_NODES + 1) inc[gi] = sh[threadIdx.x];
    if (threadIdx.x == 255) bsum[blockIdx.x] = sh[255];
}

__global__ __launch_bounds__(256) void k_scan2(int* __restrict__ bsum) {
    __shared__ int sh[256];
    int t = threadIdx.x;
    sh[t] = (t < SCAN_NB) ? bsum[t] : 0;
    __syncthreads();
    #pragma unroll
    for (int d = 1; d < 256; d <<= 1) {
        int v = (t >= d) ? sh[t - d] : 0;
        __syncthreads();
        sh[t] += v;
        __syncthreads();
    }
    if (t < SCAN_NB) bsum[t] = (t == 0) ? 0 : sh[t - 1];
}

__global__ __launch_bounds__(256) void k_scan3(const int* __restrict__ inc,
                                               const int* __restrict__ cnt,
                                               const int* __restrict__ bsum,
                                               int* __restrict__ offs) {
    int gi = blockIdx.x * 256 + threadIdx.x;
    if (gi < N_NODES + 1) offs[gi] = bsum[blockIdx.x] + inc[gi] - cnt[gi];
}

// pure random 4B store, no atomics: p = offs[d] + rank[i]
__global__ __launch_bounds__(256) void k_scatter(
    const int* __restrict__ ei, const float* __restrict__ eattr,
    const int* __restrict__ offs, const int* __restrict__ rank,
    unsigned int* __restrict__ s_pack) {
    int i = blockIdx.x * blockDim.x + threadIdx.x;
    if (i >= N_EDGES) return;
    int d = ei[N_EDGES + i];
    int p = offs[d] + rank[i];
    unsigned pk = ((unsigned)f2bf(eattr[i]) << 16) | (unsigned)(ei[i] & 0xFFFF);
    s_pack[p] = pk;
}

// ---------------- z = relu(LN(h, g, b)) (f32 + bf16 copies) ----------------
__global__ __launch_bounds__(256) void k_ln_relu(
    const float* __restrict__ h, const float* __restrict__ g,
    const float* __restrict__ b, float* __restrict__ z, unsigned short* __restrict__ zb) {
    int wid = (blockIdx.x * blockDim.x + threadIdx.x) >> 6;
    int lane = threadIdx.x & 63;
    if (wid >= N_NODES) return;
    float v = h[wid * 64 + lane];
    float sx = v, sq = v * v;
    #pragma unroll
    for (int o = 32; o > 0; o >>= 1) {
        sx += __shfl_xor(sx, o, 64);
        sq += __shfl_xor(sq, o, 64);
    }
    float mu = sx * (1.f / 64.f);
    float var = sq * (1.f / 64.f) - mu * mu;
    float zz = fmaxf((v - mu) * rsqrtf(var + 1e-5f) * g[lane] + b[lane], 0.f);
    z[wid * 64 + lane] = zz;
    zb[wid * 64 + lane] = f2bf(zz);
}

// ---------------- softmax aggregation, online, one wave per dst node ----------------
__global__ __launch_bounds__(256) void k_agg(
    const unsigned short* __restrict__ zb, const int* __restrict__ offs,
    const unsigned int* __restrict__ s_pack,
    const float* __restrict__ We, const float* __restrict__ be,
    const float* __restrict__ t, int layer, float* __restrict__ agg) {
    int wid = (blockIdx.x * blockDim.x + threadIdx.x) >> 6;
    int lane = threadIdx.x & 63;
    if (wid >= N_NODES) return;
    int beg = offs[wid], end = offs[wid + 1];
    float we = We[lane], bev = be[lane];
    float tl = t[layer];
    float m = -INFINITY, s = 0.f, num = 0.f;
    int i = beg;
    for (; i + 3 < end; i += 4) {
        unsigned pk0 = s_pack[i], pk1 = s_pack[i + 1], pk2 = s_pack[i + 2], pk3 = s_pack[i + 3];
        float z0 = bf2f(zb[(pk0 & 0xFFFFu) * 64 + lane]);
        float z1 = bf2f(zb[(pk1 & 0xFFFFu) * 64 + lane]);
        float z2 = bf2f(zb[(pk2 & 0xFFFFu) * 64 + lane]);
        float z3 = bf2f(zb[(pk3 & 0xFFFFu) * 64 + lane]);
        float msg0 = fmaxf(z0 + fmaf(bfbits_hi(pk0), we, bev), 0.f) + 1e-7f;
        float msg1 = fmaxf(z1 + fmaf(bfbits_hi(pk1), we, bev), 0.f) + 1e-7f;
        float msg2 = fmaxf(z2 + fmaf(bfbits_hi(pk2), we, bev), 0.f) + 1e-7f;
        float msg3 = fmaxf(z3 + fmaf(bfbits_hi(pk3), we, bev), 0.f) + 1e-7f;
        float lg0 = msg0 * tl, lg1 = msg1 * tl, lg2 = msg2 * tl, lg3 = msg3 * tl;
        float mn = fmaxf(m, fmaxf(fmaxf(lg0, lg1), fmaxf(lg2, lg3)));
        float corr = __expf(m - mn);
        float p0 = __expf(lg0 - mn), p1 = __expf(lg1 - mn);
        float p2 = __expf(lg2 - mn), p3 = __expf(lg3 - mn);
        s = fmaf(s, corr, (p0 + p1) + (p2 + p3));
        num = fmaf(num, corr, fmaf(p0, msg0, p1 * msg1) + fmaf(p2, msg2, p3 * msg3));
        m = mn;
    }
    for (; i < end; ++i) {
        unsigned pk = s_pack[i];
        float zz = bf2f(zb[(pk & 0xFFFFu) * 64 + lane]);
        float msg = fmaxf(zz + fmaf(bfbits_hi(pk), we, bev), 0.f) + 1e-7f;
        float lg = msg * tl;
        float mn = fmaxf(m, lg);
        float corr = __expf(m - mn);
        float p = __expf(lg - mn);
        s = fmaf(s, corr, p);
        num = fmaf(num, corr, p * msg);
        m = mn;
    }
    agg[wid * 64 + lane] = num / (s + 1e-16f);
}

// ---------------- fused MLP via MFMA bf16 (one wave per 16 nodes) ----------------
__global__ __launch_bounds__(256) void k_mlp(
    const float* __restrict__ agg, const float* __restrict__ z,
    float* __restrict__ h, const float* __restrict__ W1, const float* __restrict__ b1,
    const float* __restrict__ g1, const float* __restrict__ be1,
    const float* __restrict__ W2, const float* __restrict__ b2, int addres) {
    __shared__ unsigned short vbuf[4][16 * 64];
    __shared__ unsigned short ubuf[4][16 * 128];
    int lane = threadIdx.x & 63;
    int wave = threadIdx.x >> 6;
    int col = lane & 15, quad = lane >> 4;
    unsigned short* vb = vbuf[wave];
    unsigned short* ub = ubuf[wave];

    short8 w1f[2][8];
    #pragma unroll
    for (int s = 0; s < 2; ++s)
        #pragma unroll
        for (int t = 0; t < 8; ++t)
            #pragma unroll
            for (int j = 0; j < 8; ++j)
                w1f[s][t][j] = (short)f2bf(W1[(s * 32 + quad * 8 + j) * 128 + t * 16 + col]);
    short8 w2f[4][4];
    #pragma unroll
    for (int s = 0; s < 4; ++s)
        #pragma unroll
        for (int t = 0; t < 4; ++t)
            #pragma unroll
            for (int j = 0; j < 8; ++j)
                w2f[s][t][j] = (short)f2bf(W2[(s * 32 + quad * 8 + j) * 64 + t * 16 + col]);

    float b1f[8], g1f[8], e1f[8];
    #pragma unroll
    for (int t = 0; t < 8; ++t) {
        int ch = t * 16 + col;
        b1f[t] = b1[ch]; g1f[t] = g1[ch]; e1f[t] = be1[ch];
    }
    float b2f_[4];
    #pragma unroll
    for (int t = 0; t < 4; ++t) b2f_[t] = b2[t * 16 + col];

    int nd = lane >> 2;
    int cg = (lane & 3) * 16;

    for (int g = blockIdx.x * 4 + wave; g < N_NODES / 16; g += gridDim.x * 4) {
        int n0 = g * 16;
        const float4* ap = (const float4*)(agg + (size_t)(n0 + nd) * 64 + cg);
        const float4* zp = (const float4*)(z + (size_t)(n0 + nd) * 64 + cg);
        float vv[16];
        #pragma unroll
        for (int q = 0; q < 4; ++q) {
            float4 a4 = ap[q], z4 = zp[q];
            vv[q * 4 + 0] = a4.x + z4.x; vv[q * 4 + 1] = a4.y + z4.y;
            vv[q * 4 + 2] = a4.z + z4.z; vv[q * 4 + 3] = a4.w + z4.w;
        }
        unsigned int pk[8];
        #pragma unroll
        for (int i = 0; i < 8; ++i)
            pk[i] = (unsigned)f2bf(vv[2 * i]) | ((unsigned)f2bf(vv[2 * i + 1]) << 16);
        uint4* vdst = (uint4*)&vb[nd * 64 + cg];
        vdst[0] = make_uint4(pk[0], pk[1], pk[2], pk[3]);
        vdst[1] = make_uint4(pk[4], pk[5], pk[6], pk[7]);

        short8 a0 = *(const short8*)&vb[col * 64 + quad * 8];
        short8 a1 = *(const short8*)&vb[col * 64 + 32 + quad * 8];
        f32x4 au[8];
        #pragma unroll
        for (int t = 0; t < 8; ++t) {
            f32x4 c = {0.f, 0.f, 0.f, 0.f};
            c = __builtin_amdgcn_mfma_f32_16x16x32_bf16(a0, w1f[0][t], c, 0, 0, 0);
            c = __builtin_amdgcn_mfma_f32_16x16x32_bf16(a1, w1f[1][t], c, 0, 0, 0);
            au[t] = c;
        }
        #pragma unroll
        for (int r = 0; r < 4; ++r) {
            float sx = 0.f, sq = 0.f;
            #pragma unroll
            for (int t = 0; t < 8; ++t) {
                float v = au[t][r] + b1f[t];
                sx += v; sq += v * v;
            }
            #pragma unroll
            for (int mask = 1; mask < 16; mask <<= 1) {
                sx += __shfl_xor(sx, mask, 64);
                sq += __shfl_xor(sq, mask, 64);
            }
            float mu = sx * (1.f / 128.f);
            float var = sq * (1.f / 128.f) - mu * mu;
            float rs = rsqrtf(var + 1e-5f);
            int row = quad * 4 + r;
            #pragma unroll
            for (int t = 0; t < 8; ++t) {
                float v = au[t][r] + b1f[t];
                float y = fmaxf(fmaf((v - mu) * rs, g1f[t], e1f[t]), 0.f);
                ub[row * 128 + t * 16 + col] = f2bf(y);
            }
        }
        f32x4 oc[4];
        #pragma unroll
        for (int t = 0; t < 4; ++t) oc[t] = (f32x4){0.f, 0.f, 0.f, 0.f};
        #pragma unroll
        for (int s = 0; s < 4; ++s) {
            short8 a = *(const short8*)&ub[col * 128 + s * 32 + quad * 8];
            #pragma unroll
            for (int t = 0; t < 4; ++t)
                oc[t] = __builtin_amdgcn_mfma_f32_16x16x32_bf16(a, w2f[s][t], oc[t], 0, 0, 0);
        }
        #pragma unroll
        for (int t = 0; t < 4; ++t) {
            #pragma unroll
            for (int r = 0; r < 4; ++r) {
                int n = n0 + quad * 4 + r;
                int ch = t * 16 + col;
                float val = oc[t][r] + b2f_[t];
                float* hp = &h[(size_t)n * 64 + ch];
                if (addres) val += *hp;
                *hp = val;
            }
        }
    }
}

// ---------------- final LN/relu + pool partials (2-node ILP, fused sum/sumsq) ----------------
__global__ __launch_bounds__(256) void k_pool(
    const float* __restrict__ h, const float* __restrict__ g, const float* __restrict__ b,
    float* __restrict__ pb_sum, float* __restrict__ pb_max) {
    __shared__ float ssum[4][64];
    __shared__ float smax[4][64];
    int lane = threadIdx.x & 63;
    int wave = threadIdx.x >> 6;
    int gw = blockIdx.x * 4 + wave;
    int nw = gridDim.x * 4;
    float ga = g[lane], ba = b[lane];
    float lsum = 0.f, lmax = 0.f;
    int n = gw;
    for (; n + nw < N_NODES; n += 2 * nw) {
        int n2 = n + nw;
        float v0 = h[(size_t)n * 64 + lane];
        float v1 = h[(size_t)n2 * 64 + lane];
        float sx0 = v0, sq0 = v0 * v0, sx1 = v1, sq1 = v1 * v1;
        #pragma unroll
        for (int o = 32; o > 0; o >>= 1) {
            sx0 += __shfl_xor(sx0, o, 64);
            sq0 += __shfl_xor(sq0, o, 64);
            sx1 += __shfl_xor(sx1, o, 64);
            sq1 += __shfl_xor(sq1, o, 64);
        }
        float mu0 = sx0 * (1.f / 64.f), mu1 = sx1 * (1.f / 64.f);
        float var0 = sq0 * (1.f / 64.f) - mu0 * mu0;
        float var1 = sq1 * (1.f / 64.f) - mu1 * mu1;
        float z0 = fmaxf((v0 - mu0) * rsqrtf(var0 + 1e-5f) * ga + ba, 0.f);
        float z1 = fmaxf((v1 - mu1) * rsqrtf(var1 + 1e-5f) * ga + ba, 0.f);
        lsum += z0 + z1;
        lmax = fmaxf(lmax, fmaxf(z0, z1));
    }
    if (n < N_NODES) {
        float v = h[(size_t)n * 64 + lane];
        float sx = v, sq = v * v;
        #pragma unroll
        for (int o = 32; o > 0; o >>= 1) {
            sx += __shfl_xor(sx, o, 64);
            sq += __shfl_xor(sq, o, 64);
        }
        float mu = sx * (1.f / 64.f);
        float var = sq * (1.f / 64.f) - mu * mu;
        float zz = fmaxf((v - mu) * rsqrtf(var + 1e-5f) * ga + ba, 0.f);
        lsum += zz;
        lmax = fmaxf(lmax, zz);
    }
    ssum[wave][lane] = lsum;
    smax[wave][lane] = lmax;
    __syncthreads();
    if (wave == 0) {
        float s = ssum[0][lane] + ssum[1][lane] + ssum[2][lane] + ssum[3][lane];
        float mx = fmaxf(fmaxf(smax[0][lane], smax[1][lane]),
                         fmaxf(smax[2][lane], smax[3][lane]));
        pb_sum[blockIdx.x * 64 + lane] = s;
        pb_max[blockIdx.x * 64 + lane] = mx;
    }
}

// ---------------- head: reduce block partials -> bins -> emb @ W_lin + b_lin ----------------
__global__ __launch_bounds__(256) void k_head(
    const float* __restrict__ pb_sum, const float* __restrict__ pb_max,
    const float* __restrict__ Wl, const float* __restrict__ bl, float* __restrict__ out) {
    __shared__ float sa4[4][64], sm4[4][64];
    __shared__ float sa[64], sm[64], emb[64];
    int t = threadIdx.x;
    int ch = t & 63, part = t >> 6;          // 4 partial-slices per channel
    float s = 0.f, mx = 0.f;
    for (int b = part; b < NBP; b += 4) {
        s += pb_sum[b * 64 + ch];
        mx = fmaxf(mx, pb_max[b * 64 + ch]);
    }
    sa4[part][ch] = s; sm4[part][ch] = mx;
    __syncthreads();
    if (t < 64) {
        sa[t] = sa4[0][t] + sa4[1][t] + sa4[2][t] + sa4[3][t];
        sm[t] = fmaxf(fmaxf(sm4[0][t], sm4[1][t]), fmaxf(sm4[2][t], sm4[3][t]));
    }
    __syncthreads();
    if (t < 64) {
        if (t < 32) {
            emb[t] = (sa[2 * t] + sa[2 * t + 1]) * (0.5f / (float)N_NODES);
        } else {
            int i = t - 32;
            emb[t] = fmaxf(sm[2 * i], sm[2 * i + 1]);
        }
    }
    __syncthreads();
    if (t < 64) {
        float acc = bl[t];
        for (int k = 0; k < 64; ++k) acc = fmaf(emb[k], Wl[k * 64 + t], acc);
        out[t] = acc;
    }
}

extern "C" void kernel_launch(void* const* d_in, const int* in_sizes, int n_in,
                              void* d_out, int out_size, void* d_ws, size_t ws_size,
                              hipStream_t stream) {
    const float* x     = (const float*)d_in[0];
    const float* eattr = (const float*)d_in[1];
    const int*   ei    = (const int*)d_in[2];
    const float* Wn    = (const float*)d_in[3];
    const float* bn    = (const float*)d_in[4];
    const float* We    = (const float*)d_in[5];
    const float* be    = (const float*)d_in[6];
    const float* t     = (const float*)d_in[7];
    const float* W1    = (const float*)d_in[8];
    const float* b1    = (const float*)d_in[9];
    const float* lg    = (const float*)d_in[10];
    const float* lb    = (const float*)d_in[11];
    const float* W2    = (const float*)d_in[12];
    const float* b2    = (const float*)d_in[13];
    const float* ng    = (const float*)d_in[14];
    const float* nb    = (const float*)d_in[15];
    const float* Wl    = (const float*)d_in[16];
    const float* bl    = (const float*)d_in[17];
    float* out = (float*)d_out;

    char* p = (char*)d_ws;
    float* h   = (float*)p; p += (size_t)N_NODES * 64 * 4;
    float* z   = (float*)p; p += (size_t)N_NODES * 64 * 4;
    float* agg = (float*)p; p += (size_t)N_NODES * 64 * 4;
    unsigned short* zb = (unsigned short*)p; p += (size_t)N_NODES * 64 * 2;
    unsigned int* s_pack = (unsigned int*)p; p += (size_t)N_EDGES * 4;
    int* cnt    = (int*)p;  p += (size_t)(N_NODES + 4) * 4;
    int* offs   = (int*)p;  p += (size_t)(N_NODES + 4) * 4;
    int* inc    = (int*)p;  p += (size_t)(N_NODES + 4) * 4;
    int* bsum   = (int*)p;  p += (size_t)256 * 4;
    float* pb_sum = (float*)p; p += (size_t)NBP * 64 * 4;
    float* pb_max = (float*)p; p += (size_t)NBP * 64 * 4;
    int* rank = (int*)agg;   // aliases agg: rank dead before first k_agg write

    hipMemsetAsync(cnt, 0, (N_NODES + 1) * sizeof(int), stream);

    k_node_encode<<<(N_NODES + 3) / 4, 256, 0, stream>>>(x, Wn, bn, h, zb);
    k_hist_rank<<<(N_EDGES + 255) / 256, 256, 0, stream>>>(ei, cnt, rank);
    k_scan1<<<SCAN_NB, 256, 0, stream>>>(cnt, inc, bsum);
    k_scan2<<<1, 256, 0, stream>>>(bsum);
    k_scan3<<<SCAN_NB, 256, 0, stream>>>(inc, cnt, bsum, offs);
    k_scatter<<<(N_EDGES + 255) / 256, 256, 0, stream>>>(ei, eattr, offs, rank, s_pack);

    for (int i = 0; i < 3; ++i) {
        const float* zp;
        if (i > 0) {
            k_ln_relu<<<(N_NODES + 3) / 4, 256, 0, stream>>>(h, ng + i * 64, nb + i * 64, z, zb);
            zp = z;
        } else {
            zp = h;   // zb already holds bf16(h) from k_node_encode
        }
        k_agg<<<(N_NODES + 3) / 4, 256, 0, stream>>>(zb, offs, s_pack, We, be, t, i, agg);
        k_mlp<<<391, 256, 0, stream>>>(
            agg, zp, h, W1 + (size_t)i * 64 * 128, b1 + i * 128, lg + i * 128, lb + i * 128,
            W2 + (size_t)i * 128 * 64, b2 + i * 64, i > 0);
    }

    k_pool<<<NBP, 256, 0, stream>>>(h, ng, nb, pb_sum, pb_max);
    k_head<<<1, 256, 0, stream>>>(pb_sum, pb_max, Wl, bl, out);
}